// Round 3
// baseline (1761.348 us; speedup 1.0000x reference)
//
#include <hip/hip_runtime.h>

#define HW 65536
#define NT 4096     // 64-pixel tiles total (4 bb x 1024)
#define GS 768      // persistent grid: 3 blocks/CU x 256 CU

typedef __attribute__((ext_vector_type(8))) short short8;   // 8 bf16 = 4 VGPRs (MFMA A/B frag)
typedef __attribute__((ext_vector_type(4))) float f32x4;    // MFMA C/D frag

static __device__ __forceinline__ unsigned short f2bf(float f) {
    unsigned int u = __float_as_uint(f);
    u += 0x7FFFu + ((u >> 16) & 1u);        // RNE (inputs finite)
    return (unsigned short)(u >> 16);
}
static __device__ __forceinline__ float bf2f(unsigned short s) {
    return __uint_as_float(((unsigned int)s) << 16);
}
// HW packed conversion: lo16 = bf16(a), hi16 = bf16(b), RNE — matches f2bf
static __device__ __forceinline__ unsigned int cvt_pk_bf16(float a, float b) {
    unsigned int r;
    asm("v_cvt_pk_bf16_f32 %0, %1, %2" : "=v"(r) : "v"(a), "v"(b));
    return r;
}

// tanh-form gelu as h * sigmoid(2u):  exp(-2u) = exp2(h*(c1 + c2*h^2))
static __device__ __forceinline__ float gelu_sig(float h) {
    float h2 = h * h;
    float z  = h * __builtin_fmaf(-0.1029392f, h2, -2.3021178f);
    float ex = __builtin_amdgcn_exp2f(z);
    return h * __builtin_amdgcn_rcpf(1.0f + ex);
}
static __device__ __forceinline__ float sigmoid_fast(float v) {
    float ex = __builtin_amdgcn_exp2f(-1.4426950f * v);
    return __builtin_amdgcn_rcpf(1.0f + ex);
}

// ---- prep: transpose weights to bf16 in workspace ----
__global__ void dig_prep(const float* __restrict__ W1, const float* __restrict__ Wf,
                         unsigned short* __restrict__ w1t, unsigned short* __restrict__ wft) {
    int tid = blockIdx.x * blockDim.x + threadIdx.x;
    int stride = gridDim.x * blockDim.x;
    for (int i = tid; i < 128 * 64; i += stride) {
        int r = i >> 6, d = i & 63;
        int kind = r >> 6, e = r & 63;
        w1t[i] = f2bf(W1[(kind * 64 + d) * 64 + e]);
    }
    for (int i = tid; i < 64 * 192; i += stride) {
        int r = i / 192, c = i - r * 192;
        wft[i] = f2bf(Wf[c * 64 + r]);
    }
}

// ---- main: persistent blocks, double-buffered 64-px tiles, reg-staged prefetch ----
// LDS = 2*25600 (XS) + 2*1536 (GT) = 54272 B -> 3 blocks/CU. launch_bounds(256,3) -> 170 VGPR budget.
// 2 barriers per tile; next tile's global loads issued at body top, written to LDS at body end.
__global__ __launch_bounds__(256, 3) void dig_main(
    const float* __restrict__ x,     // [4][192][65536] fp32
    const float* __restrict__ W1,    // fallback path only
    const float* __restrict__ b1,    // [64]
    const float* __restrict__ W2,    // [64]
    const float* __restrict__ b2,    // [1]
    const float* __restrict__ Wf,    // fallback path only
    const float* __restrict__ bfv,   // [64]
    float* __restrict__ out,         // [4][64][65536] fp32
    const unsigned short* __restrict__ w1t_g,  // [128][64] bf16 (pre-transposed)
    const unsigned short* __restrict__ wft_g,  // [64][192] bf16 (pre-transposed)
    int wsok)
{
    __shared__ __align__(16) unsigned short XS[2][64 * 200];   // 2 x 25600 B
    __shared__ float GT[2][384];                               // 2 x [st][pair][pix32]

    const int tid = threadIdx.x;
    const int l   = tid & 63;
    const int w   = tid >> 6;
    const int lm  = l & 15;
    const int q   = l >> 4;

    // ---- per-thread invariants ----
    const float4 b1v4 = *(const float4*)(b1 + w * 16 + q * 4);
    const float4 w2v4 = *(const float4*)(W2 + w * 16 + q * 4);
    const float  b2v  = b2[0];
    const float b1a[4] = {b1v4.x, b1v4.y, b1v4.z, b1v4.w};
    const float w2a[4] = {w2v4.x, w2v4.y, w2v4.z, w2v4.w};

    short8 afr[2][2];   // A frags: [kind][ks], rows = kind*64 + 16w + lm
    if (wsok) {
        #pragma unroll
        for (int kind = 0; kind < 2; ++kind)
            #pragma unroll
            for (int ks = 0; ks < 2; ++ks)
                afr[kind][ks] = *(const short8*)&w1t_g[(kind * 64 + w * 16 + lm) * 64 + ks * 32 + q * 8];
    } else {
        #pragma unroll
        for (int kind = 0; kind < 2; ++kind)
            #pragma unroll
            for (int ks = 0; ks < 2; ++ks) {
                union { short8 v; unsigned short u[8]; } tmp;
                #pragma unroll
                for (int j = 0; j < 8; ++j)
                    tmp.u[j] = f2bf(W1[(kind * 64 + ks * 32 + q * 8 + j) * 64 + (w * 16 + lm)]);
                afr[kind][ks] = tmp.v;
            }
    }

    float bo[4];
    #pragma unroll
    for (int n = 0; n < 4; ++n) bo[n] = bfv[n * 16 + lm];

    // staging regs: it 0..5 -> idx = it*256+tid; pg = idx&15 (pixel group), c = (idx>>4)*2 (channel pair)
    float4 v0[6], v1[6];

    // ---------- prologue: stage first tile into XS[0] ----------
    int tc = blockIdx.x;
    {
        const int bb = tc >> 10, hw0 = (tc & 1023) * 64;
        const float* xb = x + (size_t)bb * (192 * HW) + hw0;
        #pragma unroll
        for (int it = 0; it < 6; ++it) {
            const int idx = it * 256 + tid;
            const float* pp = xb + (size_t)((idx >> 4) * 2) * HW + (idx & 15) * 4;
            v0[it] = *(const float4*)pp;
            v1[it] = *(const float4*)(pp + HW);
        }
        if (tid < 192) { GT[0][tid] = 0.f; GT[0][tid + 192] = 0.f;
                         GT[1][tid] = 0.f; GT[1][tid + 192] = 0.f; }
        #pragma unroll
        for (int it = 0; it < 6; ++it) {
            const int idx = it * 256 + tid;
            const int c = (idx >> 4) * 2, px = (idx & 15) * 4;
            *(unsigned int*)&XS[0][(px + 0) * 200 + c] = cvt_pk_bf16(v0[it].x, v1[it].x);
            *(unsigned int*)&XS[0][(px + 1) * 200 + c] = cvt_pk_bf16(v0[it].y, v1[it].y);
            *(unsigned int*)&XS[0][(px + 2) * 200 + c] = cvt_pk_bf16(v0[it].z, v1[it].z);
            *(unsigned int*)&XS[0][(px + 3) * 200 + c] = cvt_pk_bf16(v0[it].w, v1[it].w);
        }
    }
    __syncthreads();

    int p = 0;
    for (; tc < NT; tc += GS) {
        const int bb = tc >> 10, hw0 = (tc & 1023) * 64;
        const int tn = tc + GS;
        const bool hasnext = (tn < NT);

        // ---- issue next tile's loads (consumed at body end; latency hidden by B/C+E) ----
        if (hasnext) {
            const int nbb = tn >> 10, nhw0 = (tn & 1023) * 64;
            const float* xb = x + (size_t)nbb * (192 * HW) + nhw0;
            #pragma unroll
            for (int it = 0; it < 6; ++it) {
                const int idx = it * 256 + tid;
                const float* pp = xb + (size_t)((idx >> 4) * 2) * HW + (idx & 15) * 4;
                v0[it] = *(const float4*)pp;
                v1[it] = *(const float4*)(pp + HW);
            }
            // zero the other GT for the next tile (its previous readers finished before last barrier)
            if (tid < 192) { GT[p ^ 1][tid] = 0.f; GT[p ^ 1][tid + 192] = 0.f; }
        }

        const unsigned short* XSp = &XS[p][0];

        // ---------- Phase B/C: MFMA a/c + in-register gates -> GT[p] ----------
        #pragma unroll
        for (int st = 0; st < 2; ++st) {
            #pragma unroll
            for (int pt = 0; pt < 2; ++pt) {
                f32x4 acc[2][3];   // [kind][t]; lane: e = 16w+4q+reg, pix = st*32+pt*16+lm
                #pragma unroll
                for (int kind = 0; kind < 2; ++kind)
                    #pragma unroll
                    for (int t3 = 0; t3 < 3; ++t3)
                        acc[kind][t3] = (f32x4){0.f, 0.f, 0.f, 0.f};

                #pragma unroll
                for (int t3 = 0; t3 < 3; ++t3) {
                    const unsigned short* xr = &XSp[(st * 32 + pt * 16 + lm) * 200 + t3 * 64 + q * 8];
                    short8 bfr0 = *(const short8*)xr;
                    short8 bfr1 = *(const short8*)(xr + 32);
                    #pragma unroll
                    for (int kind = 0; kind < 2; ++kind) {
                        acc[kind][t3] = __builtin_amdgcn_mfma_f32_16x16x32_bf16(
                            afr[kind][0], bfr0, acc[kind][t3], 0, 0, 0);
                        acc[kind][t3] = __builtin_amdgcn_mfma_f32_16x16x32_bf16(
                            afr[kind][1], bfr1, acc[kind][t3], 0, 0, 0);
                    }
                }

                #pragma unroll
                for (int i = 0; i < 3; ++i) {
                    float ab[4];
                    #pragma unroll
                    for (int r = 0; r < 4; ++r) ab[r] = acc[0][i][r] + b1a[r];
                    #pragma unroll
                    for (int jj = 0; jj < 2; ++jj) {
                        const int j = (jj == 0) ? ((i == 0) ? 1 : 0) : ((i == 2) ? 1 : 2);
                        float pv = 0.f;
                        #pragma unroll
                        for (int r = 0; r < 4; ++r) {
                            float h = ab[r] + acc[1][j][r];
                            pv = __builtin_fmaf(w2a[r], gelu_sig(h), pv);
                        }
                        pv += __shfl_xor(pv, 16);
                        pv += __shfl_xor(pv, 32);
                        if (l < 16) atomicAdd(&GT[p][st * 192 + (2 * i + jj) * 32 + pt * 16 + lm], pv);
                    }
                }
            }
        }
        __syncthreads();

        // ---- convert prefetched tile to bf16 now (loads have long since landed) ----
        unsigned int su[24];
        if (hasnext) {
            #pragma unroll
            for (int it = 0; it < 6; ++it) {
                su[it * 4 + 0] = cvt_pk_bf16(v0[it].x, v1[it].x);
                su[it * 4 + 1] = cvt_pk_bf16(v0[it].y, v1[it].y);
                su[it * 4 + 2] = cvt_pk_bf16(v0[it].z, v1[it].z);
                su[it * 4 + 3] = cvt_pk_bf16(v0[it].w, v1[it].w);
            }
        }

        // ---------- Phase E' (fused D+E): gate rows in regs, MFMA with Wf, store ----------
        {
            const int r = w * 16 + lm;                      // XS row this lane feeds
            const unsigned short* xrow = XSp + r * 200;
            short8 fr[6];                                    // lane's 48 channels (frag 2t+P = t, d=32P+q*8)
            #pragma unroll
            for (int ks = 0; ks < 6; ++ks)
                fr[ks] = *(const short8*)&xrow[ks * 32 + q * 8];

            short8 cur[4];                                   // wft frags for ks=0 (issued early)
            if (wsok)
                #pragma unroll
                for (int n = 0; n < 4; ++n)
                    cur[n] = *(const short8*)&wft_g[(n * 16 + lm) * 192 + q * 8];

            const float* gb = &GT[p][(r >> 5) * 192];
            float g[6];
            #pragma unroll
            for (int p6 = 0; p6 < 6; ++p6)
                g[p6] = sigmoid_fast(gb[p6 * 32 + (r & 31)] + b2v);

            short8 af[6];
            #pragma unroll
            for (int P = 0; P < 2; ++P) {
                float s[3][8];
                #pragma unroll
                for (int t3 = 0; t3 < 3; ++t3) {
                    union { short8 v; unsigned short u[8]; } tt; tt.v = fr[2 * t3 + P];
                    #pragma unroll
                    for (int m = 0; m < 8; ++m) s[t3][m] = bf2f(tt.u[m]);
                }
                #pragma unroll
                for (int t3 = 0; t3 < 3; ++t3) {
                    const int j0c = (t3 == 0) ? 1 : 0;
                    const int j1c = (t3 == 2) ? 1 : 2;
                    const float g0 = g[2 * t3], g1 = g[2 * t3 + 1];
                    union { short8 v; unsigned int u[4]; } ot;
                    #pragma unroll
                    for (int m2 = 0; m2 < 4; ++m2) {
                        float e0 = __builtin_fmaf(g1, s[j1c][2 * m2],
                                   __builtin_fmaf(g0, s[j0c][2 * m2], s[t3][2 * m2]));
                        float e1 = __builtin_fmaf(g1, s[j1c][2 * m2 + 1],
                                   __builtin_fmaf(g0, s[j0c][2 * m2 + 1], s[t3][2 * m2 + 1]));
                        ot.u[m2] = cvt_pk_bf16(e0, e1);
                    }
                    af[2 * t3 + P] = ot.v;
                }
            }

            f32x4 eacc[4];
            #pragma unroll
            for (int n = 0; n < 4; ++n) eacc[n] = (f32x4){0.f, 0.f, 0.f, 0.f};

            #pragma unroll
            for (int ks = 0; ks < 6; ++ks) {
                short8 nxt[4];
                if (wsok && ks < 5)
                    #pragma unroll
                    for (int n = 0; n < 4; ++n)
                        nxt[n] = *(const short8*)&wft_g[(n * 16 + lm) * 192 + (ks + 1) * 32 + q * 8];
                if (!wsok) {
                    #pragma unroll
                    for (int n = 0; n < 4; ++n) {
                        union { short8 v; unsigned short u[8]; } tmp;
                        #pragma unroll
                        for (int j = 0; j < 8; ++j)
                            tmp.u[j] = f2bf(Wf[(ks * 32 + q * 8 + j) * 64 + n * 16 + lm]);
                        cur[n] = tmp.v;
                    }
                }
                #pragma unroll
                for (int n = 0; n < 4; ++n)
                    eacc[n] = __builtin_amdgcn_mfma_f32_16x16x32_bf16(af[ks], cur[n], eacc[n], 0, 0, 0);
                if (wsok && ks < 5)
                    #pragma unroll
                    for (int n = 0; n < 4; ++n) cur[n] = nxt[n];
            }

            float* ob = out + (size_t)bb * (64 * HW) + hw0 + w * 16 + q * 4;
            #pragma unroll
            for (int n = 0; n < 4; ++n)
                *(float4*)(ob + (size_t)(n * 16 + lm) * HW) =
                    make_float4(eacc[n][0] + bo[n], eacc[n][1] + bo[n],
                                eacc[n][2] + bo[n], eacc[n][3] + bo[n]);
        }

        // ---- write prefetched tile into the other buffer ----
        if (hasnext) {
            unsigned short* XSn = &XS[p ^ 1][0];
            #pragma unroll
            for (int it = 0; it < 6; ++it) {
                const int idx = it * 256 + tid;
                const int c = (idx >> 4) * 2, px = (idx & 15) * 4;
                *(unsigned int*)&XSn[(px + 0) * 200 + c] = su[it * 4 + 0];
                *(unsigned int*)&XSn[(px + 1) * 200 + c] = su[it * 4 + 1];
                *(unsigned int*)&XSn[(px + 2) * 200 + c] = su[it * 4 + 2];
                *(unsigned int*)&XSn[(px + 3) * 200 + c] = su[it * 4 + 3];
            }
        }
        __syncthreads();
        p ^= 1;
    }
}

extern "C" void kernel_launch(void* const* d_in, const int* in_sizes, int n_in,
                              void* d_out, int out_size, void* d_ws, size_t ws_size,
                              hipStream_t stream) {
    (void)in_sizes; (void)n_in; (void)out_size;
    const float* x  = (const float*)d_in[0];
    const float* W1 = (const float*)d_in[1];
    const float* b1 = (const float*)d_in[2];
    const float* W2 = (const float*)d_in[3];
    const float* b2 = (const float*)d_in[4];
    const float* Wf = (const float*)d_in[5];
    const float* bf = (const float*)d_in[6];
    float* out = (float*)d_out;

    unsigned short* w1t = (unsigned short*)d_ws;
    unsigned short* wft = w1t + 128 * 64;
    const size_t need = (size_t)(128 * 64 + 64 * 192) * sizeof(unsigned short);
    int wsok = (d_ws != nullptr && ws_size >= need) ? 1 : 0;

    if (wsok) dig_prep<<<dim3(80), dim3(256), 0, stream>>>(W1, Wf, w1t, wft);
    dig_main<<<dim3(GS), dim3(256), 0, stream>>>(x, W1, b1, W2, b2, Wf, bf, out,
                                                 w1t, wft, wsok);
}

// Round 4
// 610.898 us; speedup vs baseline: 2.8832x; 2.8832x over previous
//
#include <hip/hip_runtime.h>

#define HW 65536
#define NT 4096     // 64-pixel tiles (4 bb x 1024)
#define GS 768      // persistent: 3 blocks/CU x 256 CU (LDS-resident capacity)

typedef __attribute__((ext_vector_type(8))) short short8;   // 8 bf16 = 4 VGPRs (MFMA A/B frag)
typedef __attribute__((ext_vector_type(4))) float f32x4;    // MFMA C/D frag

static __device__ __forceinline__ unsigned short f2bf(float f) {
    unsigned int u = __float_as_uint(f);
    u += 0x7FFFu + ((u >> 16) & 1u);        // RNE (inputs finite)
    return (unsigned short)(u >> 16);
}
static __device__ __forceinline__ float bf2f(unsigned short s) {
    return __uint_as_float(((unsigned int)s) << 16);
}
static __device__ __forceinline__ unsigned int cvt_pk_bf16(float a, float b) {
    unsigned int r;
    asm("v_cvt_pk_bf16_f32 %0, %1, %2" : "=v"(r) : "v"(a), "v"(b));
    return r;
}

// tanh-form gelu as h * sigmoid(2u):  exp(-2u) = exp2(h*(c1 + c2*h^2))
static __device__ __forceinline__ float gelu_sig(float h) {
    float h2 = h * h;
    float z  = h * __builtin_fmaf(-0.1029392f, h2, -2.3021178f);
    float ex = __builtin_amdgcn_exp2f(z);
    return h * __builtin_amdgcn_rcpf(1.0f + ex);
}
static __device__ __forceinline__ float sigmoid_fast(float v) {
    float ex = __builtin_amdgcn_exp2f(-1.4426950f * v);
    return __builtin_amdgcn_rcpf(1.0f + ex);
}

// ---- prep: transpose weights to bf16 in workspace ----
// w1t[r][d], r = kind*64 + e: = W1[kind*64 + d][e];  wft[o][c]: = Wf[c][o]
__global__ void dig_prep(const float* __restrict__ W1, const float* __restrict__ Wf,
                         unsigned short* __restrict__ w1t, unsigned short* __restrict__ wft) {
    int tid = blockIdx.x * blockDim.x + threadIdx.x;
    int stride = gridDim.x * blockDim.x;
    for (int i = tid; i < 128 * 64; i += stride) {
        int r = i >> 6, d = i & 63;
        int kind = r >> 6, e = r & 63;
        w1t[i] = f2bf(W1[(kind * 64 + d) * 64 + e]);
    }
    for (int i = tid; i < 64 * 192; i += stride) {
        int r = i / 192, c = i - r * 192;
        wft[i] = f2bf(Wf[c * 64 + r]);
    }
}

// ---- main: persistent, double-buffered 64-px tiles, WAVE-LOCAL pipeline ----
// Wave w owns pixels [16w,16w+16): computes all 64 e per pixel -> gates via 2 shfl,
// no LDS gate buffer, no atomics, ONE barrier per tile (staging sync).
// W1 frags reloaded from L1/L2 per use (short live ranges); prefetch issued after
// gate phase frees its accumulators. LDS = 2*25600 = 51200 B -> 3 blocks/CU.
__global__ __launch_bounds__(256, 3) void dig_main(
    const float* __restrict__ x,     // [4][192][65536] fp32
    const float* __restrict__ W1,    // fallback path only
    const float* __restrict__ b1,    // [64]
    const float* __restrict__ W2,    // [64]
    const float* __restrict__ b2,    // [1]
    const float* __restrict__ Wf,    // fallback path only
    const float* __restrict__ bfv,   // [64]
    float* __restrict__ out,         // [4][64][65536] fp32
    const unsigned short* __restrict__ w1t_g,  // [128][64] bf16
    const unsigned short* __restrict__ wft_g,  // [64][192] bf16
    int wsok)
{
    __shared__ __align__(16) unsigned short XS[2][64 * 200];   // 2 x 25600 B

    const int tid = threadIdx.x;
    const int l   = tid & 63;
    const int w   = tid >> 6;
    const int lm  = l & 15;
    const int q   = l >> 4;

    // ---- permanent per-lane constants ----
    float b1a[16], w2a[16];          // e = et*16 + q*4 + r  ->  [et*4+r]
    #pragma unroll
    for (int et = 0; et < 4; ++et) {
        float4 t1 = *(const float4*)(b1 + et * 16 + q * 4);
        float4 t2 = *(const float4*)(W2 + et * 16 + q * 4);
        b1a[et * 4 + 0] = t1.x; b1a[et * 4 + 1] = t1.y; b1a[et * 4 + 2] = t1.z; b1a[et * 4 + 3] = t1.w;
        w2a[et * 4 + 0] = t2.x; w2a[et * 4 + 1] = t2.y; w2a[et * 4 + 2] = t2.z; w2a[et * 4 + 3] = t2.w;
    }
    const float b2v = b2[0];
    float bo[4];
    #pragma unroll
    for (int n = 0; n < 4; ++n) bo[n] = bfv[n * 16 + lm];

    // ---------- prologue: stage first tile into XS[0] ----------
    int tc = blockIdx.x;
    {
        const int bb = tc >> 10, hw0 = (tc & 1023) * 64;
        const float* xb = x + (size_t)bb * (192 * HW) + hw0;
        #pragma unroll
        for (int it = 0; it < 6; ++it) {
            const int idx = it * 256 + tid;
            const int c = (idx >> 4) * 2, pg = idx & 15;
            const float* pp = xb + (size_t)c * HW + pg * 4;
            float4 v0 = *(const float4*)pp;
            float4 v1 = *(const float4*)(pp + HW);
            const int px = pg * 4;
            *(unsigned int*)&XS[0][(px + 0) * 200 + c] = cvt_pk_bf16(v0.x, v1.x);
            *(unsigned int*)&XS[0][(px + 1) * 200 + c] = cvt_pk_bf16(v0.y, v1.y);
            *(unsigned int*)&XS[0][(px + 2) * 200 + c] = cvt_pk_bf16(v0.z, v1.z);
            *(unsigned int*)&XS[0][(px + 3) * 200 + c] = cvt_pk_bf16(v0.w, v1.w);
        }
    }
    __syncthreads();

    int p = 0;
    for (; tc < NT; tc += GS) {
        const int bb = tc >> 10, hw0 = (tc & 1023) * 64;
        const int rrow = w * 16 + lm;                 // this lane's pixel row (A-side + gates)

        // ---- the ONLY XS[p] reads of the tile: 6 frags = B-operands AND E A-source ----
        short8 fr[6];                                  // fr[k6] = channels k6*32 + q*8 .. +8
        {
            const unsigned short* xrow = &XS[p][rrow * 200 + q * 8];
            #pragma unroll
            for (int k6 = 0; k6 < 6; ++k6)
                fr[k6] = *(const short8*)(xrow + k6 * 32);
        }

        // ---------- B/C: per-pair MFMA + in-register gates (wave-local) ----------
        float pre[6];                                  // gate pre-acts [2i+jj]
        #pragma unroll
        for (int j = 0; j < 3; ++j) {
            f32x4 cacc[4];                             // c_j, all 64 e: [et]; e = et*16+q*4+r
            {
                short8 cw[8];                          // W1 kind=1 frags, transient
                if (wsok) {
                    #pragma unroll
                    for (int et = 0; et < 4; ++et)
                        #pragma unroll
                        for (int ks = 0; ks < 2; ++ks)
                            cw[et * 2 + ks] = *(const short8*)&w1t_g[(64 + et * 16 + lm) * 64 + ks * 32 + q * 8];
                } else {
                    #pragma unroll
                    for (int et = 0; et < 4; ++et)
                        #pragma unroll
                        for (int ks = 0; ks < 2; ++ks) {
                            union { short8 v; unsigned short u[8]; } tmp;
                            #pragma unroll
                            for (int jj2 = 0; jj2 < 8; ++jj2)
                                tmp.u[jj2] = f2bf(W1[(64 + ks * 32 + q * 8 + jj2) * 64 + (et * 16 + lm)]);
                            cw[et * 2 + ks] = tmp.v;
                        }
                }
                #pragma unroll
                for (int et = 0; et < 4; ++et) {
                    cacc[et] = __builtin_amdgcn_mfma_f32_16x16x32_bf16(
                        cw[et * 2 + 0], fr[2 * j + 0], (f32x4){0.f, 0.f, 0.f, 0.f}, 0, 0, 0);
                    cacc[et] = __builtin_amdgcn_mfma_f32_16x16x32_bf16(
                        cw[et * 2 + 1], fr[2 * j + 1], cacc[et], 0, 0, 0);
                }
            }
            #pragma unroll
            for (int ii = 0; ii < 2; ++ii) {
                const int i  = (j == 0) ? (ii == 0 ? 1 : 2)
                             : (j == 1) ? (ii == 0 ? 0 : 2)
                                        : (ii == 0 ? 0 : 1);
                const int jj = (j == ((i == 2) ? 1 : 2)) ? 1 : 0;

                f32x4 aacc[4];                         // a_i, all 64 e (recomputed per pair)
                {
                    short8 aw[8];                      // W1 kind=0 frags, transient
                    if (wsok) {
                        #pragma unroll
                        for (int et = 0; et < 4; ++et)
                            #pragma unroll
                            for (int ks = 0; ks < 2; ++ks)
                                aw[et * 2 + ks] = *(const short8*)&w1t_g[(et * 16 + lm) * 64 + ks * 32 + q * 8];
                    } else {
                        #pragma unroll
                        for (int et = 0; et < 4; ++et)
                            #pragma unroll
                            for (int ks = 0; ks < 2; ++ks) {
                                union { short8 v; unsigned short u[8]; } tmp;
                                #pragma unroll
                                for (int jj2 = 0; jj2 < 8; ++jj2)
                                    tmp.u[jj2] = f2bf(W1[(ks * 32 + q * 8 + jj2) * 64 + (et * 16 + lm)]);
                                aw[et * 2 + ks] = tmp.v;
                            }
                    }
                    #pragma unroll
                    for (int et = 0; et < 4; ++et) {
                        aacc[et] = __builtin_amdgcn_mfma_f32_16x16x32_bf16(
                            aw[et * 2 + 0], fr[2 * i + 0], (f32x4){0.f, 0.f, 0.f, 0.f}, 0, 0, 0);
                        aacc[et] = __builtin_amdgcn_mfma_f32_16x16x32_bf16(
                            aw[et * 2 + 1], fr[2 * i + 1], aacc[et], 0, 0, 0);
                    }
                }

                float pv = 0.f;
                #pragma unroll
                for (int et = 0; et < 4; ++et)
                    #pragma unroll
                    for (int r = 0; r < 4; ++r) {
                        float h = aacc[et][r] + cacc[et][r] + b1a[et * 4 + r];
                        pv = __builtin_fmaf(w2a[et * 4 + r], gelu_sig(h), pv);
                    }
                pv += __shfl_xor(pv, 16);              // reduce over q (e-quads)
                pv += __shfl_xor(pv, 32);
                pre[2 * i + jj] = pv;                  // full 64-e sum, pixel = rrow
            }
        }

        float g[6];
        #pragma unroll
        for (int p6 = 0; p6 < 6; ++p6)
            g[p6] = sigmoid_fast(pre[p6] + b2v);

        // ---------- D in registers: af[k6] = gated channels of row rrow ----------
        short8 af[6];
        #pragma unroll
        for (int P = 0; P < 2; ++P) {
            float s[3][8];
            #pragma unroll
            for (int t3 = 0; t3 < 3; ++t3) {
                union { short8 v; unsigned short u[8]; } tt; tt.v = fr[2 * t3 + P];
                #pragma unroll
                for (int m = 0; m < 8; ++m) s[t3][m] = bf2f(tt.u[m]);
            }
            #pragma unroll
            for (int t3 = 0; t3 < 3; ++t3) {
                const int j0c = (t3 == 0) ? 1 : 0;
                const int j1c = (t3 == 2) ? 1 : 2;
                const float g0 = g[2 * t3], g1 = g[2 * t3 + 1];
                union { short8 v; unsigned int u[4]; } ot;
                #pragma unroll
                for (int m2 = 0; m2 < 4; ++m2) {
                    float e0 = __builtin_fmaf(g1, s[j1c][2 * m2],
                               __builtin_fmaf(g0, s[j0c][2 * m2], s[t3][2 * m2]));
                    float e1 = __builtin_fmaf(g1, s[j1c][2 * m2 + 1],
                               __builtin_fmaf(g0, s[j0c][2 * m2 + 1], s[t3][2 * m2 + 1]));
                    ot.u[m2] = cvt_pk_bf16(e0, e1);
                }
                af[2 * t3 + P] = ot.v;
            }
        }

        // ---- issue next tile's loads (fr dead; gate accs dead -> regs free) ----
        const bool hasnext = (tc + GS < NT);
        float4 v0[6], v1[6];
        if (hasnext) {
            const int tn = tc + GS;
            const float* xb = x + (size_t)(tn >> 10) * (192 * HW) + (tn & 1023) * 64;
            #pragma unroll
            for (int it = 0; it < 6; ++it) {
                const int idx = it * 256 + tid;
                const float* pp = xb + (size_t)((idx >> 4) * 2) * HW + (idx & 15) * 4;
                v0[it] = *(const float4*)pp;
                v1[it] = *(const float4*)(pp + HW);
            }
        }

        // ---------- E: out rows = af @ Wf^T; latency of v0/v1 hidden here ----------
        {
            f32x4 eacc[4];
            #pragma unroll
            for (int n = 0; n < 4; ++n) eacc[n] = (f32x4){0.f, 0.f, 0.f, 0.f};
            #pragma unroll
            for (int k6 = 0; k6 < 6; ++k6) {
                #pragma unroll
                for (int n = 0; n < 4; ++n) {
                    short8 bw;
                    if (wsok) {
                        bw = *(const short8*)&wft_g[(n * 16 + lm) * 192 + k6 * 32 + q * 8];
                    } else {
                        union { short8 v; unsigned short u[8]; } tmp;
                        #pragma unroll
                        for (int jj2 = 0; jj2 < 8; ++jj2)
                            tmp.u[jj2] = f2bf(Wf[(k6 * 32 + q * 8 + jj2) * 64 + n * 16 + lm]);
                        bw = tmp.v;
                    }
                    eacc[n] = __builtin_amdgcn_mfma_f32_16x16x32_bf16(af[k6], bw, eacc[n], 0, 0, 0);
                }
            }
            float* ob = out + (size_t)bb * (64 * HW) + hw0 + w * 16 + q * 4;
            #pragma unroll
            for (int n = 0; n < 4; ++n)
                *(float4*)(ob + (size_t)(n * 16 + lm) * HW) =
                    make_float4(eacc[n][0] + bo[n], eacc[n][1] + bo[n],
                                eacc[n][2] + bo[n], eacc[n][3] + bo[n]);
        }

        // ---- convert + write prefetched tile into the other buffer ----
        if (hasnext) {
            unsigned short* XSn = &XS[p ^ 1][0];
            #pragma unroll
            for (int it = 0; it < 6; ++it) {
                const int idx = it * 256 + tid;
                const int c = (idx >> 4) * 2, px = (idx & 15) * 4;
                *(unsigned int*)&XSn[(px + 0) * 200 + c] = cvt_pk_bf16(v0[it].x, v1[it].x);
                *(unsigned int*)&XSn[(px + 1) * 200 + c] = cvt_pk_bf16(v0[it].y, v1[it].y);
                *(unsigned int*)&XSn[(px + 2) * 200 + c] = cvt_pk_bf16(v0[it].z, v1[it].z);
                *(unsigned int*)&XSn[(px + 3) * 200 + c] = cvt_pk_bf16(v0[it].w, v1[it].w);
            }
        }
        __syncthreads();                               // the tile's single barrier
        p ^= 1;
    }
}

extern "C" void kernel_launch(void* const* d_in, const int* in_sizes, int n_in,
                              void* d_out, int out_size, void* d_ws, size_t ws_size,
                              hipStream_t stream) {
    (void)in_sizes; (void)n_in; (void)out_size;
    const float* x  = (const float*)d_in[0];
    const float* W1 = (const float*)d_in[1];
    const float* b1 = (const float*)d_in[2];
    const float* W2 = (const float*)d_in[3];
    const float* b2 = (const float*)d_in[4];
    const float* Wf = (const float*)d_in[5];
    const float* bf = (const float*)d_in[6];
    float* out = (float*)d_out;

    unsigned short* w1t = (unsigned short*)d_ws;
    unsigned short* wft = w1t + 128 * 64;
    const size_t need = (size_t)(128 * 64 + 64 * 192) * sizeof(unsigned short);
    int wsok = (d_ws != nullptr && ws_size >= need) ? 1 : 0;

    if (wsok) dig_prep<<<dim3(80), dim3(256), 0, stream>>>(W1, Wf, w1t, wft);
    dig_main<<<dim3(GS), dim3(256), 0, stream>>>(x, W1, b1, W2, b2, Wf, bf, out,
                                                 w1t, wft, wsok);
}

// Round 5
// 402.511 us; speedup vs baseline: 4.3759x; 1.5177x over previous
//
#include <hip/hip_runtime.h>

#define HW 65536
#define NT 4096     // 64-pixel tiles (4 bb x 1024)
#define GS 512      // persistent: 2 blocks/CU x 256 CU (LDS 64KB/block)

typedef __attribute__((ext_vector_type(8))) short short8;       // 8 bf16 (MFMA A/B frag)
typedef __attribute__((ext_vector_type(4))) float f32x4;        // MFMA C/D frag
typedef __attribute__((ext_vector_type(4))) unsigned int u32x4; // frag builder

static __device__ __forceinline__ unsigned short f2bf(float f) {
    unsigned int u = __float_as_uint(f);
    u += 0x7FFFu + ((u >> 16) & 1u);        // RNE (inputs finite)
    return (unsigned short)(u >> 16);
}
static __device__ __forceinline__ float bf2f(unsigned short s) {
    return __uint_as_float(((unsigned int)s) << 16);
}
// HW packed conversion: lo16 = bf16(a), hi16 = bf16(b), RNE — matches f2bf
static __device__ __forceinline__ unsigned int cvt_pk_bf16(float a, float b) {
    unsigned int r;
    asm("v_cvt_pk_bf16_f32 %0, %1, %2" : "=v"(r) : "v"(a), "v"(b));
    return r;
}

// tanh-form gelu as h * sigmoid(2u):  exp(-2u) = exp2(h*(c1 + c2*h^2))
static __device__ __forceinline__ float gelu_sig(float h) {
    float h2 = h * h;
    float z  = h * __builtin_fmaf(-0.1029392f, h2, -2.3021178f);
    float ex = __builtin_amdgcn_exp2f(z);
    return h * __builtin_amdgcn_rcpf(1.0f + ex);
}
static __device__ __forceinline__ float sigmoid_fast(float v) {
    float ex = __builtin_amdgcn_exp2f(-1.4426950f * v);
    return __builtin_amdgcn_rcpf(1.0f + ex);
}

// swizzled W1S read: row*128B rows would be 16-way bank conflicted; XOR row&7 into bits 4-6.
// (ks*64 + q*16 occupies bits 4-6 exactly, row*128 bits >=7 -> no-carry identity.)
static __device__ __forceinline__ short8 w1frag(const unsigned char* W1SB, int row, int ks, int q) {
    const int byte = row * 128 + ((ks * 64 + q * 16) ^ ((row & 7) << 4));
    return *(const short8*)(W1SB + byte);
}

// ---- prep: transpose weights to bf16 in workspace ----
// w1t[r][d], r = kind*64 + e: = W1[kind*64 + d][e];  wft[o][c]: = Wf[c][o]
__global__ void dig_prep(const float* __restrict__ W1, const float* __restrict__ Wf,
                         unsigned short* __restrict__ w1t, unsigned short* __restrict__ wft) {
    int tid = blockIdx.x * blockDim.x + threadIdx.x;
    int stride = gridDim.x * blockDim.x;
    for (int i = tid; i < 128 * 64; i += stride) {
        int r = i >> 6, d = i & 63;
        int kind = r >> 6, e = r & 63;
        w1t[i] = f2bf(W1[(kind * 64 + d) * 64 + e]);
    }
    for (int i = tid; i < 64 * 192; i += stride) {
        int r = i / 192, c = i - r * 192;
        wft[i] = f2bf(Wf[c * 64 + r]);
    }
}

// ---- main: persistent blocks; async global_load_lds prefetch (zero staging VGPRs) ----
// LDS: XSf fp32 tile [192][64] = 49152 B + W1S (swizzled bf16 w1t) 16384 B = 65536 B -> 2 blocks/CU.
// In-loop, ALL operands come from LDS (lgkm) or persistent regs; the only vmem are the
// 12 DMA prefetch issues + out stores -> vmcnt never blocks compute (in-order counter safe).
__global__ __launch_bounds__(256, 2) void dig_main(
    const float* __restrict__ x,     // [4][192][65536] fp32
    const float* __restrict__ W1,    // fallback path only
    const float* __restrict__ b1,    // [64]
    const float* __restrict__ W2,    // [64]
    const float* __restrict__ b2,    // [1]
    const float* __restrict__ Wf,    // fallback path only
    const float* __restrict__ bfv,   // [64]
    float* __restrict__ out,         // [4][64][65536] fp32
    const unsigned short* __restrict__ w1t_g,  // [128][64] bf16
    const unsigned short* __restrict__ wft_g,  // [64][192] bf16
    int wsok)
{
    __shared__ __align__(16) float XSf[192 * 64];           // 49152 B, fp32 x tile [c][pix]
    __shared__ __align__(16) unsigned char W1SB[16384];     // swizzled w1t bf16

    const int tid = threadIdx.x;
    const int l   = tid & 63;
    const int w   = tid >> 6;
    const int lm  = l & 15;
    const int q   = l >> 4;

    // ---------- persistent per-lane state (loaded once; NEVER reloaded in loop) ----------
    float b1a[16], w2a[16];          // e = et*16 + q*4 + r -> [et*4+r]
    #pragma unroll
    for (int et = 0; et < 4; ++et) {
        float4 t1 = *(const float4*)(b1 + et * 16 + q * 4);
        float4 t2 = *(const float4*)(W2 + et * 16 + q * 4);
        b1a[et * 4 + 0] = t1.x; b1a[et * 4 + 1] = t1.y; b1a[et * 4 + 2] = t1.z; b1a[et * 4 + 3] = t1.w;
        w2a[et * 4 + 0] = t2.x; w2a[et * 4 + 1] = t2.y; w2a[et * 4 + 2] = t2.z; w2a[et * 4 + 3] = t2.w;
    }
    const float b2v = b2[0];
    float bo[4];
    #pragma unroll
    for (int n = 0; n < 4; ++n) bo[n] = bfv[n * 16 + lm];

    short8 wf[6][4];                 // persistent Wf^T frags: rows n*16+lm, ch k6*32+q*8
    if (wsok) {
        #pragma unroll
        for (int k6 = 0; k6 < 6; ++k6)
            #pragma unroll
            for (int n = 0; n < 4; ++n)
                wf[k6][n] = *(const short8*)&wft_g[(n * 16 + lm) * 192 + k6 * 32 + q * 8];
    } else {
        #pragma unroll
        for (int k6 = 0; k6 < 6; ++k6)
            #pragma unroll
            for (int n = 0; n < 4; ++n) {
                u32x4 uu;
                #pragma unroll
                for (int m2 = 0; m2 < 4; ++m2) {
                    unsigned int lo = f2bf(Wf[(k6 * 32 + q * 8 + 2 * m2 + 0) * 64 + n * 16 + lm]);
                    unsigned int hi = f2bf(Wf[(k6 * 32 + q * 8 + 2 * m2 + 1) * 64 + n * 16 + lm]);
                    uu[m2] = lo | (hi << 16);
                }
                wf[k6][n] = __builtin_bit_cast(short8, uu);
            }
    }

    // ---------- W1 -> LDS (swizzled), once per block ----------
    if (wsok) {
        #pragma unroll
        for (int it = 0; it < 4; ++it) {
            const int e8 = it * 256 + tid;              // 1024 chunks of 8 elems
            const int r = e8 >> 3, d0 = (e8 & 7) * 8;
            short8 v = *(const short8*)&w1t_g[r * 64 + d0];
            const int byte = r * 128 + ((d0 * 2) ^ ((r & 7) << 4));
            *(short8*)(W1SB + byte) = v;
        }
    } else {
        for (int i = tid; i < 128 * 64; i += 256) {
            const int r = i >> 6, d = i & 63;
            const float v = W1[((r >> 6) * 64 + d) * 64 + (r & 63)];
            const int byte = r * 128 + ((d * 2) ^ ((r & 7) << 4));
            *(unsigned short*)(W1SB + byte) = f2bf(v);
        }
    }

    // async DMA stage of tile (tcv) into XSf: 12 insts/wave, 4 channel-rows each, zero VGPR data.
#define STAGE(tcv) do {                                                                   \
        const int _bb = (tcv) >> 10, _hw0 = ((tcv) & 1023) * 64;                          \
        const float* _xb = x + (size_t)_bb * (192 * HW) + _hw0;                           \
        _Pragma("unroll")                                                                 \
        for (int _s = 0; _s < 12; ++_s) {                                                 \
            const int _cb = w * 48 + _s * 4;                                              \
            const float* _src = _xb + (size_t)(_cb + (l >> 4)) * HW + (l & 15) * 4;       \
            __builtin_amdgcn_global_load_lds(                                             \
                (const __attribute__((address_space(1))) void*)_src,                      \
                (__attribute__((address_space(3))) void*)&XSf[_cb * 64], 16, 0, 0);       \
        }                                                                                 \
    } while (0)

    // ---------- prologue: stage first tile ----------
    STAGE(blockIdx.x);
    __syncthreads();                                    // drains vmcnt (DMA) + lgkm (W1S writes)

    for (int tc = blockIdx.x; tc < NT; tc += GS) {
        const int bb = tc >> 10, hw0 = (tc & 1023) * 64;
        const int rrow = w * 16 + lm;                   // this lane's pixel row

        // ---------- fr build: the ONLY XSf reads of the tile (fp32 -> bf16 frags) ----------
        short8 fr[6];                                   // fr[k6] = channels k6*32+q*8 .. +8
        {
            const float* xf = XSf + rrow;
            #pragma unroll
            for (int k6 = 0; k6 < 6; ++k6) {
                u32x4 uu;
                #pragma unroll
                for (int m = 0; m < 4; ++m) {
                    const float a = xf[(k6 * 32 + q * 8 + 2 * m + 0) * 64];
                    const float b = xf[(k6 * 32 + q * 8 + 2 * m + 1) * 64];
                    uu[m] = cvt_pk_bf16(a, b);
                }
                fr[k6] = __builtin_bit_cast(short8, uu);
            }
        }
        __syncthreads();                                // all waves done reading XSf

        // ---------- issue next tile's DMA (overwrites XSf during compute) ----------
        if (tc + GS < NT) STAGE(tc + GS);

        // ---------- B/C: per-pair MFMA + in-register gates (weights from LDS, lgkm-only) ----------
        float pre[6];                                   // gate pre-acts [2i+jj]
        #pragma unroll
        for (int j = 0; j < 3; ++j) {
            f32x4 cacc[4];                              // c_j, all 64 e: [et]; e = et*16+q*4+r
            #pragma unroll
            for (int et = 0; et < 4; ++et) {
                short8 c0 = w1frag(W1SB, 64 + et * 16 + lm, 0, q);
                short8 c1 = w1frag(W1SB, 64 + et * 16 + lm, 1, q);
                cacc[et] = __builtin_amdgcn_mfma_f32_16x16x32_bf16(
                    c0, fr[2 * j + 0], (f32x4){0.f, 0.f, 0.f, 0.f}, 0, 0, 0);
                cacc[et] = __builtin_amdgcn_mfma_f32_16x16x32_bf16(
                    c1, fr[2 * j + 1], cacc[et], 0, 0, 0);
            }
            #pragma unroll
            for (int ii = 0; ii < 2; ++ii) {
                const int i  = (j == 0) ? (ii == 0 ? 1 : 2)
                             : (j == 1) ? (ii == 0 ? 0 : 2)
                                        : (ii == 0 ? 0 : 1);
                const int jj = (j == ((i == 2) ? 1 : 2)) ? 1 : 0;

                f32x4 aacc[4];                          // a_i, all 64 e (recomputed per pair)
                #pragma unroll
                for (int et = 0; et < 4; ++et) {
                    short8 a0 = w1frag(W1SB, et * 16 + lm, 0, q);
                    short8 a1 = w1frag(W1SB, et * 16 + lm, 1, q);
                    aacc[et] = __builtin_amdgcn_mfma_f32_16x16x32_bf16(
                        a0, fr[2 * i + 0], (f32x4){0.f, 0.f, 0.f, 0.f}, 0, 0, 0);
                    aacc[et] = __builtin_amdgcn_mfma_f32_16x16x32_bf16(
                        a1, fr[2 * i + 1], aacc[et], 0, 0, 0);
                }

                float pv = 0.f;
                #pragma unroll
                for (int et = 0; et < 4; ++et)
                    #pragma unroll
                    for (int r = 0; r < 4; ++r) {
                        float h = aacc[et][r] + cacc[et][r] + b1a[et * 4 + r];
                        pv = __builtin_fmaf(w2a[et * 4 + r], gelu_sig(h), pv);
                    }
                pv += __shfl_xor(pv, 16);               // reduce over q (e-quads)
                pv += __shfl_xor(pv, 32);
                pre[2 * i + jj] = pv;
            }
        }

        float g[6];
        #pragma unroll
        for (int p6 = 0; p6 < 6; ++p6)
            g[p6] = sigmoid_fast(pre[p6] + b2v);

        // ---------- D in registers: af[k6] = gated channels of row rrow ----------
        short8 af[6];
        #pragma unroll
        for (int P = 0; P < 2; ++P) {
            float s[3][8];
            #pragma unroll
            for (int t3 = 0; t3 < 3; ++t3)
                #pragma unroll
                for (int m = 0; m < 8; ++m)
                    s[t3][m] = bf2f((unsigned short)fr[2 * t3 + P][m]);
            #pragma unroll
            for (int t3 = 0; t3 < 3; ++t3) {
                const int j0c = (t3 == 0) ? 1 : 0;
                const int j1c = (t3 == 2) ? 1 : 2;
                const float g0 = g[2 * t3], g1 = g[2 * t3 + 1];
                u32x4 ou;
                #pragma unroll
                for (int m2 = 0; m2 < 4; ++m2) {
                    float e0 = __builtin_fmaf(g1, s[j1c][2 * m2 + 0],
                               __builtin_fmaf(g0, s[j0c][2 * m2 + 0], s[t3][2 * m2 + 0]));
                    float e1 = __builtin_fmaf(g1, s[j1c][2 * m2 + 1],
                               __builtin_fmaf(g0, s[j0c][2 * m2 + 1], s[t3][2 * m2 + 1]));
                    ou[m2] = cvt_pk_bf16(e0, e1);
                }
                af[2 * t3 + P] = __builtin_bit_cast(short8, ou);
            }
        }

        // ---------- E: pure-register MFMA with persistent wf frags; store ----------
        {
            f32x4 eacc[4];
            #pragma unroll
            for (int n = 0; n < 4; ++n) eacc[n] = (f32x4){0.f, 0.f, 0.f, 0.f};
            #pragma unroll
            for (int k6 = 0; k6 < 6; ++k6)
                #pragma unroll
                for (int n = 0; n < 4; ++n)
                    eacc[n] = __builtin_amdgcn_mfma_f32_16x16x32_bf16(af[k6], wf[k6][n], eacc[n], 0, 0, 0);

            float* ob = out + (size_t)bb * (64 * HW) + hw0 + w * 16 + q * 4;
            #pragma unroll
            for (int n = 0; n < 4; ++n)
                *(float4*)(ob + (size_t)(n * 16 + lm) * HW) =
                    make_float4(eacc[n][0] + bo[n], eacc[n][1] + bo[n],
                                eacc[n][2] + bo[n], eacc[n][3] + bo[n]);
        }

        __syncthreads();                                // drains vmcnt -> next tile staged
    }
#undef STAGE
}

extern "C" void kernel_launch(void* const* d_in, const int* in_sizes, int n_in,
                              void* d_out, int out_size, void* d_ws, size_t ws_size,
                              hipStream_t stream) {
    (void)in_sizes; (void)n_in; (void)out_size;
    const float* x  = (const float*)d_in[0];
    const float* W1 = (const float*)d_in[1];
    const float* b1 = (const float*)d_in[2];
    const float* W2 = (const float*)d_in[3];
    const float* b2 = (const float*)d_in[4];
    const float* Wf = (const float*)d_in[5];
    const float* bf = (const float*)d_in[6];
    float* out = (float*)d_out;

    unsigned short* w1t = (unsigned short*)d_ws;
    unsigned short* wft = w1t + 128 * 64;
    const size_t need = (size_t)(128 * 64 + 64 * 192) * sizeof(unsigned short);
    int wsok = (d_ws != nullptr && ws_size >= need) ? 1 : 0;

    if (wsok) dig_prep<<<dim3(80), dim3(256), 0, stream>>>(W1, Wf, w1t, wft);
    dig_main<<<dim3(GS), dim3(256), 0, stream>>>(x, W1, b1, W2, b2, Wf, bf, out,
                                                 w1t, wft, wsok);
}